// Round 1
// baseline (1114.356 us; speedup 1.0000x reference)
//
#include <hip/hip_runtime.h>

#define N_USERS 100000
#define N_ITEMS 50000
#define DIM 64

// One wave (64 lanes) per edge; lane = dim index.
// x row is selected from two base pointers split at `split` (for the concat
// case); pass split=INT_MAX and a==b for the single-embedding case.
__global__ void spmm_scatter(const int* __restrict__ rows,
                             const int* __restrict__ cols,
                             const float* __restrict__ vals,
                             const float* __restrict__ emb_a,
                             const float* __restrict__ emb_b,
                             float* __restrict__ out,
                             int nnz, int split) {
    const int lane  = threadIdx.x & 63;
    const int wave  = (blockIdx.x * blockDim.x + threadIdx.x) >> 6;
    const int nwave = (gridDim.x * blockDim.x) >> 6;
    for (int e = wave; e < nnz; e += nwave) {
        const int   r = rows[e];
        const int   c = cols[e];
        const float v = vals[e];
        const float* xrow = (c < split) ? (emb_a + (size_t)c * DIM)
                                        : (emb_b + (size_t)(c - split) * DIM);
        // HW fp32 atomic add (global_atomic_add_f32); plain atomicAdd may
        // lower to a CAS loop without -munsafe-fp-atomics.
        unsafeAtomicAdd(out + (size_t)r * DIM + lane, v * xrow[lane]);
    }
}

extern "C" void kernel_launch(void* const* d_in, const int* in_sizes, int n_in,
                              void* d_out, int out_size, void* d_ws, size_t ws_size,
                              hipStream_t stream) {
    const float* user_emb  = (const float*)d_in[0];
    const float* item_emb  = (const float*)d_in[1];
    const int*   full_rows = (const int*)d_in[2];
    const int*   full_cols = (const int*)d_in[3];
    const float* full_vals = (const float*)d_in[4];
    const int*   user_rows = (const int*)d_in[5];
    const int*   user_cols = (const int*)d_in[6];
    const float* user_vals = (const float*)d_in[7];
    const int*   item_rows = (const int*)d_in[8];
    const int*   item_cols = (const int*)d_in[9];
    const float* item_vals = (const float*)d_in[10];

    float* out = (float*)d_out;

    const int nnz_full = in_sizes[2];
    const int nnz_user = in_sizes[5];
    const int nnz_item = in_sizes[8];

    // Output layout (flat, fp32):
    //   [0,            9.6M)  all_emb1 (user_emb1 then item_emb1 — contiguous)
    //   [9.6M,  16.0M)        user_emb2
    //   [16.0M, 19.2M)        item_emb2
    float* all1  = out;
    float* user2 = out + (size_t)(N_USERS + N_ITEMS) * DIM;
    float* item2 = user2 + (size_t)N_USERS * DIM;

    hipMemsetAsync(d_out, 0, (size_t)out_size * sizeof(float), stream);

    const dim3 block(256);
    const int  grid = 4096;  // 16384 waves; grid-stride over edges

    spmm_scatter<<<grid, block, 0, stream>>>(
        full_rows, full_cols, full_vals, user_emb, item_emb, all1,
        nnz_full, N_USERS);
    spmm_scatter<<<grid, block, 0, stream>>>(
        user_rows, user_cols, user_vals, user_emb, user_emb, user2,
        nnz_user, 0x7fffffff);
    spmm_scatter<<<grid, block, 0, stream>>>(
        item_rows, item_cols, item_vals, item_emb, item_emb, item2,
        nnz_item, 0x7fffffff);
}

// Round 2
// 1077.870 us; speedup vs baseline: 1.0339x; 1.0339x over previous
//
#include <hip/hip_runtime.h>

#define NR_FULL 150000
#define NR_USER 100000
#define NR_ITEM 50000
#define NR_TOT  300000
#define NUSR    100000
#define DIM     64

#define SCAN_BS    256
#define SCAN_ITEMS 8
#define SCAN_CHUNK 2048                                  // SCAN_BS*SCAN_ITEMS
#define NBLK ((NR_TOT + SCAN_CHUNK - 1) / SCAN_CHUNK)    // 147

static_assert(NBLK <= SCAN_BS, "block-sum scan must fit one block");

// ---------------- phase kernels (CSR build) ----------------

__global__ void hist_kernel(const int* __restrict__ rows, int nnz,
                            int* __restrict__ counts) {
    int i = blockIdx.x * blockDim.x + threadIdx.x;
    int stride = gridDim.x * blockDim.x;
    for (; i < nnz; i += stride) atomicAdd(&counts[rows[i]], 1);
}

__global__ void scan_block_sums(const int* __restrict__ counts, int n,
                                int* __restrict__ bsums) {
    __shared__ int lds[SCAN_BS];
    int t = threadIdx.x;
    int base = blockIdx.x * SCAN_CHUNK;
    int s = 0;
    for (int k = 0; k < SCAN_ITEMS; ++k) {
        int idx = base + t * SCAN_ITEMS + k;
        if (idx < n) s += counts[idx];
    }
    lds[t] = s; __syncthreads();
    for (int off = SCAN_BS / 2; off > 0; off >>= 1) {
        if (t < off) lds[t] += lds[t + off];
        __syncthreads();
    }
    if (t == 0) bsums[blockIdx.x] = lds[0];
}

__global__ void scan_small_exclusive(int* __restrict__ data, int n) {
    __shared__ int lds[SCAN_BS];
    int t = threadIdx.x;
    int v = (t < n) ? data[t] : 0;
    lds[t] = v; __syncthreads();
    for (int off = 1; off < SCAN_BS; off <<= 1) {
        int add = (t >= off) ? lds[t - off] : 0;
        __syncthreads();
        lds[t] += add;
        __syncthreads();
    }
    if (t < n) data[t] = (t == 0) ? 0 : lds[t - 1];
}

__global__ void scan_apply(const int* __restrict__ counts, int n,
                           const int* __restrict__ bsums,
                           int* __restrict__ offsets, int* __restrict__ cursor,
                           int nnz_tot) {
    __shared__ int lds[SCAN_BS];
    int t = threadIdx.x, b = blockIdx.x;
    int base = b * SCAN_CHUNK;
    int v[SCAN_ITEMS];
    int s = 0;
    for (int k = 0; k < SCAN_ITEMS; ++k) {
        int idx = base + t * SCAN_ITEMS + k;
        v[k] = (idx < n) ? counts[idx] : 0;
        s += v[k];
    }
    lds[t] = s; __syncthreads();
    for (int off = 1; off < SCAN_BS; off <<= 1) {
        int add = (t >= off) ? lds[t - off] : 0;
        __syncthreads();
        lds[t] += add;
        __syncthreads();
    }
    int run = bsums[b] + ((t == 0) ? 0 : lds[t - 1]);
    for (int k = 0; k < SCAN_ITEMS; ++k) {
        int idx = base + t * SCAN_ITEMS + k;
        if (idx < n) { offsets[idx] = run; cursor[idx] = run; }
        run += v[k];
    }
    if (b == 0 && t == 0) offsets[n] = nnz_tot;
}

__global__ void scatter_kernel(const int* __restrict__ rows,
                               const int* __restrict__ cols,
                               const float* __restrict__ vals, int nnz,
                               int rowbase, int* __restrict__ cursor,
                               int2* __restrict__ pairs) {
    int i = blockIdx.x * blockDim.x + threadIdx.x;
    int stride = gridDim.x * blockDim.x;
    for (; i < nnz; i += stride) {
        int r = rows[i] + rowbase;
        int p = atomicAdd(&cursor[r], 1);
        pairs[p] = make_int2(cols[i], __float_as_int(vals[i]));
    }
}

// ---------------- segmented SpMM: one wave per global row ----------------
// Global row space g in [0, 300K): [0,150K) all1 (x = concat split at 100K),
// [150K,250K) user2, [250K,300K) item2.  Output is simply out + g*64.

__global__ void spmm_csr(const int* __restrict__ offsets,
                         const int2* __restrict__ pairs,
                         const float* __restrict__ user_emb,
                         const float* __restrict__ item_emb,
                         float* __restrict__ out) {
    const int lane = threadIdx.x & 63;
    int wave  = (blockIdx.x * blockDim.x + threadIdx.x) >> 6;
    int nwave = (gridDim.x * blockDim.x) >> 6;
    for (int g = wave; g < NR_TOT; g += nwave) {
        int beg = offsets[g], end = offsets[g + 1];
        const float *xa, *xb; int split;
        if (g < NR_FULL)                 { xa = user_emb; xb = item_emb; split = NUSR; }
        else if (g < NR_FULL + NR_USER)  { xa = xb = user_emb; split = 0x7fffffff; }
        else                             { xa = xb = item_emb; split = 0x7fffffff; }
        float acc = 0.f;
        for (int e = beg; e < end; ++e) {
            int2 p = pairs[e];
            const float* xrow = (p.x < split) ? xa + (size_t)p.x * DIM
                                              : xb + (size_t)(p.x - split) * DIM;
            acc = fmaf(__int_as_float(p.y), xrow[lane], acc);
        }
        out[(size_t)g * DIM + lane] = acc;
    }
}

// ---------------- fallback (round-1 atomic scatter) ----------------

__global__ void spmm_scatter(const int* __restrict__ rows,
                             const int* __restrict__ cols,
                             const float* __restrict__ vals,
                             const float* __restrict__ emb_a,
                             const float* __restrict__ emb_b,
                             float* __restrict__ out,
                             int nnz, int split) {
    const int lane  = threadIdx.x & 63;
    const int wave  = (blockIdx.x * blockDim.x + threadIdx.x) >> 6;
    const int nwave = (gridDim.x * blockDim.x) >> 6;
    for (int e = wave; e < nnz; e += nwave) {
        const int   r = rows[e];
        const int   c = cols[e];
        const float v = vals[e];
        const float* xrow = (c < split) ? (emb_a + (size_t)c * DIM)
                                        : (emb_b + (size_t)(c - split) * DIM);
        unsafeAtomicAdd(out + (size_t)r * DIM + lane, v * xrow[lane]);
    }
}

extern "C" void kernel_launch(void* const* d_in, const int* in_sizes, int n_in,
                              void* d_out, int out_size, void* d_ws, size_t ws_size,
                              hipStream_t stream) {
    const float* user_emb  = (const float*)d_in[0];
    const float* item_emb  = (const float*)d_in[1];
    const int*   full_rows = (const int*)d_in[2];
    const int*   full_cols = (const int*)d_in[3];
    const float* full_vals = (const float*)d_in[4];
    const int*   user_rows = (const int*)d_in[5];
    const int*   user_cols = (const int*)d_in[6];
    const float* user_vals = (const float*)d_in[7];
    const int*   item_rows = (const int*)d_in[8];
    const int*   item_cols = (const int*)d_in[9];
    const float* item_vals = (const float*)d_in[10];

    float* out = (float*)d_out;

    const int nnz_full = in_sizes[2];
    const int nnz_user = in_sizes[5];
    const int nnz_item = in_sizes[8];
    const int nnz_tot  = nnz_full + nnz_user + nnz_item;

    // workspace carve (ints), pairs 8B-aligned
    size_t i_counts  = 0;
    size_t i_offsets = i_counts + NR_TOT;            // NR_TOT+1 entries
    size_t i_cursor  = i_offsets + NR_TOT + 1;
    size_t i_bsums   = i_cursor + NR_TOT;
    size_t i_end     = i_bsums + SCAN_BS;
    if (i_end & 1) ++i_end;                          // 8B-align pairs
    size_t ws_needed = i_end * sizeof(int) + (size_t)nnz_tot * sizeof(int2);

    if (ws_size < ws_needed) {
        // fallback: atomic scatter (round-1 path)
        float* all1  = out;
        float* user2 = out + (size_t)NR_FULL * DIM;
        float* item2 = user2 + (size_t)NR_USER * DIM;
        hipMemsetAsync(d_out, 0, (size_t)out_size * sizeof(float), stream);
        spmm_scatter<<<4096, 256, 0, stream>>>(full_rows, full_cols, full_vals,
                                               user_emb, item_emb, all1, nnz_full, NUSR);
        spmm_scatter<<<4096, 256, 0, stream>>>(user_rows, user_cols, user_vals,
                                               user_emb, user_emb, user2, nnz_user, 0x7fffffff);
        spmm_scatter<<<4096, 256, 0, stream>>>(item_rows, item_cols, item_vals,
                                               item_emb, item_emb, item2, nnz_item, 0x7fffffff);
        return;
    }

    int*  ws_i    = (int*)d_ws;
    int*  counts  = ws_i + i_counts;
    int*  offsets = ws_i + i_offsets;
    int*  cursor  = ws_i + i_cursor;
    int*  bsums   = ws_i + i_bsums;
    int2* pairs   = (int2*)(ws_i + i_end);

    hipMemsetAsync(counts, 0, NR_TOT * sizeof(int), stream);

    // 1) histogram rows into global row space
    hist_kernel<<<1024, 256, 0, stream>>>(full_rows, nnz_full, counts);
    hist_kernel<<<1024, 256, 0, stream>>>(user_rows, nnz_user, counts + NR_FULL);
    hist_kernel<<<1024, 256, 0, stream>>>(item_rows, nnz_item, counts + NR_FULL + NR_USER);

    // 2) exclusive scan -> offsets (and cursor copy)
    scan_block_sums<<<NBLK, SCAN_BS, 0, stream>>>(counts, NR_TOT, bsums);
    scan_small_exclusive<<<1, SCAN_BS, 0, stream>>>(bsums, NBLK);
    scan_apply<<<NBLK, SCAN_BS, 0, stream>>>(counts, NR_TOT, bsums, offsets, cursor, nnz_tot);

    // 3) scatter edges into row-sorted (col,val) pairs
    scatter_kernel<<<1024, 256, 0, stream>>>(full_rows, full_cols, full_vals,
                                             nnz_full, 0, cursor, pairs);
    scatter_kernel<<<1024, 256, 0, stream>>>(user_rows, user_cols, user_vals,
                                             nnz_user, NR_FULL, cursor, pairs);
    scatter_kernel<<<1024, 256, 0, stream>>>(item_rows, item_cols, item_vals,
                                             nnz_item, NR_FULL + NR_USER, cursor, pairs);

    // 4) segmented SpMM, one wave per global row, one store per row
    spmm_csr<<<2048, 256, 0, stream>>>(offsets, pairs, user_emb, item_emb, out);
}

// Round 3
// 876.688 us; speedup vs baseline: 1.2711x; 1.2295x over previous
//
#include <hip/hip_runtime.h>

#define NR_FULL 150000
#define NR_USER 100000
#define NR_ITEM 50000
#define NR_TOT  300000
#define NUSR    100000
#define DIM     64

#define SCAN_BS    256
#define SCAN_ITEMS 8
#define SCAN_CHUNK 2048
#define NBLK ((NR_TOT + SCAN_CHUNK - 1) / SCAN_CHUNK)    // 147

static_assert(NBLK <= SCAN_BS, "block-sum scan must fit one block");

typedef __attribute__((ext_vector_type(4))) float f32x4;

// ---------------- CSR build ----------------

// One fused histogram over the three row arrays (global row space).
__global__ void hist_all(const int* __restrict__ r_full, int n_full,
                         const int* __restrict__ r_user, int n_user,
                         const int* __restrict__ r_item, int n_item,
                         int* __restrict__ counts) {
    int i = blockIdx.x * blockDim.x + threadIdx.x;
    int stride = gridDim.x * blockDim.x;
    int n_tot = n_full + n_user + n_item;
    for (; i < n_tot; i += stride) {
        int r;
        if (i < n_full)                r = r_full[i];
        else if (i < n_full + n_user)  r = r_user[i - n_full] + NR_FULL;
        else                           r = r_item[i - n_full - n_user] + NR_FULL + NR_USER;
        atomicAdd(&counts[r], 1);
    }
}

__global__ void scan_block_sums(const int* __restrict__ counts, int n,
                                int* __restrict__ bsums) {
    __shared__ int lds[SCAN_BS];
    int t = threadIdx.x;
    int base = blockIdx.x * SCAN_CHUNK;
    int s = 0;
    for (int k = 0; k < SCAN_ITEMS; ++k) {
        int idx = base + t * SCAN_ITEMS + k;
        if (idx < n) s += counts[idx];
    }
    lds[t] = s; __syncthreads();
    for (int off = SCAN_BS / 2; off > 0; off >>= 1) {
        if (t < off) lds[t] += lds[t + off];
        __syncthreads();
    }
    if (t == 0) bsums[blockIdx.x] = lds[0];
}

__global__ void scan_small_exclusive(int* __restrict__ data, int n) {
    __shared__ int lds[SCAN_BS];
    int t = threadIdx.x;
    int v = (t < n) ? data[t] : 0;
    lds[t] = v; __syncthreads();
    for (int off = 1; off < SCAN_BS; off <<= 1) {
        int add = (t >= off) ? lds[t - off] : 0;
        __syncthreads();
        lds[t] += add;
        __syncthreads();
    }
    if (t < n) data[t] = (t == 0) ? 0 : lds[t - 1];
}

__global__ void scan_apply(const int* __restrict__ counts, int n,
                           const int* __restrict__ bsums,
                           int* __restrict__ offsets, int* __restrict__ cursor,
                           int nnz_tot) {
    __shared__ int lds[SCAN_BS];
    int t = threadIdx.x, b = blockIdx.x;
    int base = b * SCAN_CHUNK;
    int v[SCAN_ITEMS];
    int s = 0;
    for (int k = 0; k < SCAN_ITEMS; ++k) {
        int idx = base + t * SCAN_ITEMS + k;
        v[k] = (idx < n) ? counts[idx] : 0;
        s += v[k];
    }
    lds[t] = s; __syncthreads();
    for (int off = 1; off < SCAN_BS; off <<= 1) {
        int add = (t >= off) ? lds[t - off] : 0;
        __syncthreads();
        lds[t] += add;
        __syncthreads();
    }
    int run = bsums[b] + ((t == 0) ? 0 : lds[t - 1]);
    for (int k = 0; k < SCAN_ITEMS; ++k) {
        int idx = base + t * SCAN_ITEMS + k;
        if (idx < n) { offsets[idx] = run; cursor[idx] = run; }
        run += v[k];
    }
    if (b == 0 && t == 0) offsets[n] = nnz_tot;
}

// Fused scatter: edges -> row-grouped (col,val) packed 8B, NT stores so the
// 34MB random-write stream doesn't thrash L2 (write-once, read-once-next-kernel).
__global__ void scatter_all(const int* __restrict__ r_full,
                            const int* __restrict__ c_full,
                            const float* __restrict__ v_full, int n_full,
                            const int* __restrict__ r_user,
                            const int* __restrict__ c_user,
                            const float* __restrict__ v_user, int n_user,
                            const int* __restrict__ r_item,
                            const int* __restrict__ c_item,
                            const float* __restrict__ v_item, int n_item,
                            int* __restrict__ cursor,
                            long long* __restrict__ pairs) {
    int i = blockIdx.x * blockDim.x + threadIdx.x;
    int stride = gridDim.x * blockDim.x;
    int n_tot = n_full + n_user + n_item;
    for (; i < n_tot; i += stride) {
        int r, c; float v;
        if (i < n_full) {
            r = r_full[i];                              c = c_full[i];  v = v_full[i];
        } else if (i < n_full + n_user) {
            int j = i - n_full;
            r = r_user[j] + NR_FULL;                    c = c_user[j];  v = v_user[j];
        } else {
            int j = i - n_full - n_user;
            r = r_item[j] + NR_FULL + NR_USER;          c = c_item[j];  v = v_item[j];
        }
        int p = atomicAdd(&cursor[r], 1);
        long long packed = ((long long)__float_as_int(v) << 32) | (unsigned int)c;
        __builtin_nontemporal_store(packed, &pairs[p]);
    }
}

// ---------------- segmented SpMM: one wave per global row ----------------
// 4 x 16-lane groups; group handles one edge; lane loads float4 (16x16B=row).
// 4 gathers in flight per wave-iteration; cross-group shuffle reduce; one
// 256B NT store per row.

__global__ void spmm_csr_v2(const int* __restrict__ offsets,
                            const long long* __restrict__ pairs,
                            const float* __restrict__ user_emb,
                            const float* __restrict__ item_emb,
                            float* __restrict__ out) {
    const int lane = threadIdx.x & 63;
    const int sub  = lane & 15;   // float4 slot within the 64-dim row
    const int grp  = lane >> 4;   // edge group 0..3
    int wave  = (blockIdx.x * blockDim.x + threadIdx.x) >> 6;
    int nwave = (gridDim.x * blockDim.x) >> 6;
    for (int g = wave; g < NR_TOT; g += nwave) {
        int beg = offsets[g], end = offsets[g + 1];
        const float *xa, *xb; int split;
        if (g < NR_FULL) {
            xa = user_emb; xb = item_emb - (size_t)NUSR * DIM; split = NUSR;
        } else if (g < NR_FULL + NR_USER) {
            xa = xb = user_emb; split = 0x7fffffff;
        } else {
            xa = xb = item_emb; split = 0x7fffffff;
        }
        f32x4 acc = {0.f, 0.f, 0.f, 0.f};
        for (int e = beg + grp; e < end; e += 4) {
            long long pe = __builtin_nontemporal_load(&pairs[e]);  // bcast in group
            int   c = (int)(unsigned int)pe;
            float v = __int_as_float((int)(pe >> 32));
            const float* base = (c < split) ? xa : xb;
            const f32x4* xrow4 = (const f32x4*)(base + (size_t)c * DIM) + sub;
            f32x4 x = *xrow4;
            acc.x = fmaf(v, x.x, acc.x);
            acc.y = fmaf(v, x.y, acc.y);
            acc.z = fmaf(v, x.z, acc.z);
            acc.w = fmaf(v, x.w, acc.w);
        }
        // combine the 4 edge-groups (lanes with equal sub)
        acc.x += __shfl_xor(acc.x, 16); acc.y += __shfl_xor(acc.y, 16);
        acc.z += __shfl_xor(acc.z, 16); acc.w += __shfl_xor(acc.w, 16);
        acc.x += __shfl_xor(acc.x, 32); acc.y += __shfl_xor(acc.y, 32);
        acc.z += __shfl_xor(acc.z, 32); acc.w += __shfl_xor(acc.w, 32);
        if (grp == 0) {
            f32x4* o = (f32x4*)(out + (size_t)g * DIM) + sub;
            __builtin_nontemporal_store(acc, o);
        }
    }
}

// ---------------- fallback (round-1 atomic scatter) ----------------

__global__ void spmm_scatter(const int* __restrict__ rows,
                             const int* __restrict__ cols,
                             const float* __restrict__ vals,
                             const float* __restrict__ emb_a,
                             const float* __restrict__ emb_b,
                             float* __restrict__ out,
                             int nnz, int split) {
    const int lane  = threadIdx.x & 63;
    const int wave  = (blockIdx.x * blockDim.x + threadIdx.x) >> 6;
    const int nwave = (gridDim.x * blockDim.x) >> 6;
    for (int e = wave; e < nnz; e += nwave) {
        const int   r = rows[e];
        const int   c = cols[e];
        const float v = vals[e];
        const float* xrow = (c < split) ? (emb_a + (size_t)c * DIM)
                                        : (emb_b + (size_t)(c - split) * DIM);
        unsafeAtomicAdd(out + (size_t)r * DIM + lane, v * xrow[lane]);
    }
}

extern "C" void kernel_launch(void* const* d_in, const int* in_sizes, int n_in,
                              void* d_out, int out_size, void* d_ws, size_t ws_size,
                              hipStream_t stream) {
    const float* user_emb  = (const float*)d_in[0];
    const float* item_emb  = (const float*)d_in[1];
    const int*   full_rows = (const int*)d_in[2];
    const int*   full_cols = (const int*)d_in[3];
    const float* full_vals = (const float*)d_in[4];
    const int*   user_rows = (const int*)d_in[5];
    const int*   user_cols = (const int*)d_in[6];
    const float* user_vals = (const float*)d_in[7];
    const int*   item_rows = (const int*)d_in[8];
    const int*   item_cols = (const int*)d_in[9];
    const float* item_vals = (const float*)d_in[10];

    float* out = (float*)d_out;

    const int nnz_full = in_sizes[2];
    const int nnz_user = in_sizes[5];
    const int nnz_item = in_sizes[8];
    const int nnz_tot  = nnz_full + nnz_user + nnz_item;

    size_t i_counts  = 0;
    size_t i_offsets = i_counts + NR_TOT;            // NR_TOT+1 entries
    size_t i_cursor  = i_offsets + NR_TOT + 1;
    size_t i_bsums   = i_cursor + NR_TOT;
    size_t i_end     = i_bsums + SCAN_BS;
    if (i_end & 1) ++i_end;                          // 8B-align pairs
    size_t ws_needed = i_end * sizeof(int) + (size_t)nnz_tot * sizeof(long long);

    if (ws_size < ws_needed) {
        float* all1  = out;
        float* user2 = out + (size_t)NR_FULL * DIM;
        float* item2 = user2 + (size_t)NR_USER * DIM;
        hipMemsetAsync(d_out, 0, (size_t)out_size * sizeof(float), stream);
        spmm_scatter<<<4096, 256, 0, stream>>>(full_rows, full_cols, full_vals,
                                               user_emb, item_emb, all1, nnz_full, NUSR);
        spmm_scatter<<<4096, 256, 0, stream>>>(user_rows, user_cols, user_vals,
                                               user_emb, user_emb, user2, nnz_user, 0x7fffffff);
        spmm_scatter<<<4096, 256, 0, stream>>>(item_rows, item_cols, item_vals,
                                               item_emb, item_emb, item2, nnz_item, 0x7fffffff);
        return;
    }

    int*       ws_i    = (int*)d_ws;
    int*       counts  = ws_i + i_counts;
    int*       offsets = ws_i + i_offsets;
    int*       cursor  = ws_i + i_cursor;
    int*       bsums   = ws_i + i_bsums;
    long long* pairs   = (long long*)(ws_i + i_end);

    hipMemsetAsync(counts, 0, NR_TOT * sizeof(int), stream);

    hist_all<<<2048, 256, 0, stream>>>(full_rows, nnz_full,
                                       user_rows, nnz_user,
                                       item_rows, nnz_item, counts);

    scan_block_sums<<<NBLK, SCAN_BS, 0, stream>>>(counts, NR_TOT, bsums);
    scan_small_exclusive<<<1, SCAN_BS, 0, stream>>>(bsums, NBLK);
    scan_apply<<<NBLK, SCAN_BS, 0, stream>>>(counts, NR_TOT, bsums, offsets, cursor, nnz_tot);

    scatter_all<<<2048, 256, 0, stream>>>(full_rows, full_cols, full_vals, nnz_full,
                                          user_rows, user_cols, user_vals, nnz_user,
                                          item_rows, item_cols, item_vals, nnz_item,
                                          cursor, pairs);

    spmm_csr_v2<<<4096, 256, 0, stream>>>(offsets, pairs, user_emb, item_emb, out);
}

// Round 4
// 831.026 us; speedup vs baseline: 1.3409x; 1.0549x over previous
//
#include <hip/hip_runtime.h>

#define NR_FULL 150000
#define NR_USER 100000
#define NR_ITEM 50000
#define NR_TOT  300000
#define NUSR    100000
#define DIM     64

#define SCAN_BS    256
#define SCAN_ITEMS 8
#define SCAN_CHUNK 2048
#define NBLK ((NR_TOT + SCAN_CHUNK - 1) / SCAN_CHUNK)    // 147

static_assert(NBLK <= SCAN_BS, "block-sum scan must fit one block");

typedef __attribute__((ext_vector_type(4))) float f32x4;

// ---------------- CSR build ----------------

// Vectorized histogram: 4 edges/thread-iteration, fire-and-forget atomics.
__global__ void hist_one(const int* __restrict__ rows, int nnz, int rowbase,
                         int* __restrict__ counts) {
    int t = blockIdx.x * blockDim.x + threadIdx.x;
    int stride = gridDim.x * blockDim.x;
    int nvec = nnz >> 2;
    for (int i = t; i < nvec; i += stride) {
        int4 r4 = ((const int4*)rows)[i];
        atomicAdd(&counts[r4.x + rowbase], 1);
        atomicAdd(&counts[r4.y + rowbase], 1);
        atomicAdd(&counts[r4.z + rowbase], 1);
        atomicAdd(&counts[r4.w + rowbase], 1);
    }
    for (int i = (nvec << 2) + t; i < nnz; i += stride)
        atomicAdd(&counts[rows[i] + rowbase], 1);
}

__global__ void scan_block_sums(const int* __restrict__ counts, int n,
                                int* __restrict__ bsums) {
    __shared__ int lds[SCAN_BS];
    int t = threadIdx.x;
    int base = blockIdx.x * SCAN_CHUNK;
    int s = 0;
    for (int k = 0; k < SCAN_ITEMS; ++k) {
        int idx = base + t * SCAN_ITEMS + k;
        if (idx < n) s += counts[idx];
    }
    lds[t] = s; __syncthreads();
    for (int off = SCAN_BS / 2; off > 0; off >>= 1) {
        if (t < off) lds[t] += lds[t + off];
        __syncthreads();
    }
    if (t == 0) bsums[blockIdx.x] = lds[0];
}

__global__ void scan_small_exclusive(int* __restrict__ data, int n) {
    __shared__ int lds[SCAN_BS];
    int t = threadIdx.x;
    int v = (t < n) ? data[t] : 0;
    lds[t] = v; __syncthreads();
    for (int off = 1; off < SCAN_BS; off <<= 1) {
        int add = (t >= off) ? lds[t - off] : 0;
        __syncthreads();
        lds[t] += add;
        __syncthreads();
    }
    if (t < n) data[t] = (t == 0) ? 0 : lds[t - 1];
}

__global__ void scan_apply(const int* __restrict__ counts, int n,
                           const int* __restrict__ bsums,
                           int* __restrict__ offsets, int* __restrict__ cursor,
                           int nnz_tot) {
    __shared__ int lds[SCAN_BS];
    int t = threadIdx.x, b = blockIdx.x;
    int base = b * SCAN_CHUNK;
    int v[SCAN_ITEMS];
    int s = 0;
    for (int k = 0; k < SCAN_ITEMS; ++k) {
        int idx = base + t * SCAN_ITEMS + k;
        v[k] = (idx < n) ? counts[idx] : 0;
        s += v[k];
    }
    lds[t] = s; __syncthreads();
    for (int off = 1; off < SCAN_BS; off <<= 1) {
        int add = (t >= off) ? lds[t - off] : 0;
        __syncthreads();
        lds[t] += add;
        __syncthreads();
    }
    int run = bsums[b] + ((t == 0) ? 0 : lds[t - 1]);
    for (int k = 0; k < SCAN_ITEMS; ++k) {
        int idx = base + t * SCAN_ITEMS + k;
        if (idx < n) { offsets[idx] = run; cursor[idx] = run; }
        run += v[k];
    }
    if (b == 0 && t == 0) offsets[n] = nnz_tot;
}

// Vectorized scatter: 4 edges/iteration -> 4 returning atomics in flight,
// then 4 independent stores. Plain (L2-cached) stores so partial-line writes
// merge in L2 (NT here caused 9.6x HBM write amplification in round 3).
__global__ void scatter_one(const int* __restrict__ rows,
                            const int* __restrict__ cols,
                            const float* __restrict__ vals, int nnz,
                            int rowbase, int* __restrict__ cursor,
                            long long* __restrict__ pairs) {
    int t = blockIdx.x * blockDim.x + threadIdx.x;
    int stride = gridDim.x * blockDim.x;
    int nvec = nnz >> 2;
    for (int i = t; i < nvec; i += stride) {
        int4   r4 = ((const int4*)rows)[i];
        int4   c4 = ((const int4*)cols)[i];
        float4 v4 = ((const float4*)vals)[i];
        int p0 = atomicAdd(&cursor[r4.x + rowbase], 1);
        int p1 = atomicAdd(&cursor[r4.y + rowbase], 1);
        int p2 = atomicAdd(&cursor[r4.z + rowbase], 1);
        int p3 = atomicAdd(&cursor[r4.w + rowbase], 1);
        pairs[p0] = ((long long)__float_as_int(v4.x) << 32) | (unsigned int)c4.x;
        pairs[p1] = ((long long)__float_as_int(v4.y) << 32) | (unsigned int)c4.y;
        pairs[p2] = ((long long)__float_as_int(v4.z) << 32) | (unsigned int)c4.z;
        pairs[p3] = ((long long)__float_as_int(v4.w) << 32) | (unsigned int)c4.w;
    }
    for (int i = (nvec << 2) + t; i < nnz; i += stride) {
        int p = atomicAdd(&cursor[rows[i] + rowbase], 1);
        pairs[p] = ((long long)__float_as_int(vals[i]) << 32) | (unsigned int)cols[i];
    }
}

// ---------------- segmented SpMM: one wave per global row ----------------
// 4 x 16-lane groups; group handles one edge; lane loads float4 (16x16B=row).

__global__ void spmm_csr_v2(const int* __restrict__ offsets,
                            const long long* __restrict__ pairs,
                            const float* __restrict__ user_emb,
                            const float* __restrict__ item_emb,
                            float* __restrict__ out) {
    const int lane = threadIdx.x & 63;
    const int sub  = lane & 15;   // float4 slot within the 64-dim row
    const int grp  = lane >> 4;   // edge group 0..3
    int wave  = (blockIdx.x * blockDim.x + threadIdx.x) >> 6;
    int nwave = (gridDim.x * blockDim.x) >> 6;
    for (int g = wave; g < NR_TOT; g += nwave) {
        int beg = offsets[g], end = offsets[g + 1];
        const float *xa, *xb; int split;
        if (g < NR_FULL) {
            xa = user_emb; xb = item_emb - (size_t)NUSR * DIM; split = NUSR;
        } else if (g < NR_FULL + NR_USER) {
            xa = xb = user_emb; split = 0x7fffffff;
        } else {
            xa = xb = item_emb; split = 0x7fffffff;
        }
        f32x4 acc = {0.f, 0.f, 0.f, 0.f};
        for (int e = beg + grp; e < end; e += 4) {
            long long pe = __builtin_nontemporal_load(&pairs[e]);
            int   c = (int)(unsigned int)pe;
            float v = __int_as_float((int)(pe >> 32));
            const float* base = (c < split) ? xa : xb;
            const f32x4* xrow4 = (const f32x4*)(base + (size_t)c * DIM) + sub;
            f32x4 x = *xrow4;
            acc.x = fmaf(v, x.x, acc.x);
            acc.y = fmaf(v, x.y, acc.y);
            acc.z = fmaf(v, x.z, acc.z);
            acc.w = fmaf(v, x.w, acc.w);
        }
        acc.x += __shfl_xor(acc.x, 16); acc.y += __shfl_xor(acc.y, 16);
        acc.z += __shfl_xor(acc.z, 16); acc.w += __shfl_xor(acc.w, 16);
        acc.x += __shfl_xor(acc.x, 32); acc.y += __shfl_xor(acc.y, 32);
        acc.z += __shfl_xor(acc.z, 32); acc.w += __shfl_xor(acc.w, 32);
        if (grp == 0) {
            f32x4* o = (f32x4*)(out + (size_t)g * DIM) + sub;
            __builtin_nontemporal_store(acc, o);
        }
    }
}

// ---------------- fallback (round-1 atomic scatter) ----------------

__global__ void spmm_scatter(const int* __restrict__ rows,
                             const int* __restrict__ cols,
                             const float* __restrict__ vals,
                             const float* __restrict__ emb_a,
                             const float* __restrict__ emb_b,
                             float* __restrict__ out,
                             int nnz, int split) {
    const int lane  = threadIdx.x & 63;
    const int wave  = (blockIdx.x * blockDim.x + threadIdx.x) >> 6;
    const int nwave = (gridDim.x * blockDim.x) >> 6;
    for (int e = wave; e < nnz; e += nwave) {
        const int   r = rows[e];
        const int   c = cols[e];
        const float v = vals[e];
        const float* xrow = (c < split) ? (emb_a + (size_t)c * DIM)
                                        : (emb_b + (size_t)(c - split) * DIM);
        unsafeAtomicAdd(out + (size_t)r * DIM + lane, v * xrow[lane]);
    }
}

static inline int grid_for(int work, int cap) {
    int g = (work + 255) / 256;
    return g < cap ? (g > 1 ? g : 1) : cap;
}

extern "C" void kernel_launch(void* const* d_in, const int* in_sizes, int n_in,
                              void* d_out, int out_size, void* d_ws, size_t ws_size,
                              hipStream_t stream) {
    const float* user_emb  = (const float*)d_in[0];
    const float* item_emb  = (const float*)d_in[1];
    const int*   full_rows = (const int*)d_in[2];
    const int*   full_cols = (const int*)d_in[3];
    const float* full_vals = (const float*)d_in[4];
    const int*   user_rows = (const int*)d_in[5];
    const int*   user_cols = (const int*)d_in[6];
    const float* user_vals = (const float*)d_in[7];
    const int*   item_rows = (const int*)d_in[8];
    const int*   item_cols = (const int*)d_in[9];
    const float* item_vals = (const float*)d_in[10];

    float* out = (float*)d_out;

    const int nnz_full = in_sizes[2];
    const int nnz_user = in_sizes[5];
    const int nnz_item = in_sizes[8];
    const int nnz_tot  = nnz_full + nnz_user + nnz_item;

    size_t i_counts  = 0;
    size_t i_offsets = i_counts + NR_TOT;            // NR_TOT+1 entries
    size_t i_cursor  = i_offsets + NR_TOT + 1;
    size_t i_bsums   = i_cursor + NR_TOT;
    size_t i_end     = i_bsums + SCAN_BS;
    if (i_end & 1) ++i_end;                          // 8B-align pairs
    size_t ws_needed = i_end * sizeof(int) + (size_t)nnz_tot * sizeof(long long);

    if (ws_size < ws_needed) {
        float* all1  = out;
        float* user2 = out + (size_t)NR_FULL * DIM;
        float* item2 = user2 + (size_t)NR_USER * DIM;
        hipMemsetAsync(d_out, 0, (size_t)out_size * sizeof(float), stream);
        spmm_scatter<<<4096, 256, 0, stream>>>(full_rows, full_cols, full_vals,
                                               user_emb, item_emb, all1, nnz_full, NUSR);
        spmm_scatter<<<4096, 256, 0, stream>>>(user_rows, user_cols, user_vals,
                                               user_emb, user_emb, user2, nnz_user, 0x7fffffff);
        spmm_scatter<<<4096, 256, 0, stream>>>(item_rows, item_cols, item_vals,
                                               item_emb, item_emb, item2, nnz_item, 0x7fffffff);
        return;
    }

    int*       ws_i    = (int*)d_ws;
    int*       counts  = ws_i + i_counts;
    int*       offsets = ws_i + i_offsets;
    int*       cursor  = ws_i + i_cursor;
    int*       bsums   = ws_i + i_bsums;
    long long* pairs   = (long long*)(ws_i + i_end);

    hipMemsetAsync(counts, 0, NR_TOT * sizeof(int), stream);

    hist_one<<<grid_for(nnz_full / 4, 2048), 256, 0, stream>>>(full_rows, nnz_full, 0, counts);
    hist_one<<<grid_for(nnz_user / 4, 2048), 256, 0, stream>>>(user_rows, nnz_user, NR_FULL, counts);
    hist_one<<<grid_for(nnz_item / 4, 2048), 256, 0, stream>>>(item_rows, nnz_item, NR_FULL + NR_USER, counts);

    scan_block_sums<<<NBLK, SCAN_BS, 0, stream>>>(counts, NR_TOT, bsums);
    scan_small_exclusive<<<1, SCAN_BS, 0, stream>>>(bsums, NBLK);
    scan_apply<<<NBLK, SCAN_BS, 0, stream>>>(counts, NR_TOT, bsums, offsets, cursor, nnz_tot);

    scatter_one<<<grid_for(nnz_full / 4, 2048), 256, 0, stream>>>(
        full_rows, full_cols, full_vals, nnz_full, 0, cursor, pairs);
    scatter_one<<<grid_for(nnz_user / 4, 2048), 256, 0, stream>>>(
        user_rows, user_cols, user_vals, nnz_user, NR_FULL, cursor, pairs);
    scatter_one<<<grid_for(nnz_item / 4, 2048), 256, 0, stream>>>(
        item_rows, item_cols, item_vals, nnz_item, NR_FULL + NR_USER, cursor, pairs);

    spmm_csr_v2<<<4096, 256, 0, stream>>>(offsets, pairs, user_emb, item_emb, out);
}